// Round 2
// baseline (147.599 us; speedup 1.0000x reference)
//
#include <hip/hip_runtime.h>
#include <stdint.h>

#define TILE_LEN 16
#define KMAX 64
#define IMGW 512
#define IMGH 512
#define TXN (IMGW / TILE_LEN)   // 32
#define TYN (IMGH / TILE_LEN)   // 32
#define ROWCAP 4096             // per-row bin capacity (expected ~900)

// ---------------------------------------------------------------------------
// Kernel 1: per-gaussian prep + row binning.
// pA = (px, py, radius, opacity); pB = (a, b, c, det); pC = (r, g, b, 0)
// indexed by ORIGINAL gaussian index. Each gaussian appends its index to
// every tile-row whose exact y-overlap test passes (same _rn arithmetic as
// the reference's overlap test). Append order is nondeterministic; the sort
// kernel makes the final order deterministic via unique keys.
// ---------------------------------------------------------------------------
__global__ __launch_bounds__(256) void prep(
    const float* __restrict__ pos2d, const float* __restrict__ cov2d,
    const float* __restrict__ opac,  const float* __restrict__ color,
    float4* __restrict__ pA, float4* __restrict__ pB, float4* __restrict__ pC,
    int* __restrict__ counts, int* __restrict__ bins, int N)
{
    const int i = blockIdx.x * 256 + threadIdx.x;
    if (i >= N) return;

    const float a = cov2d[4 * i + 0];
    const float b = cov2d[4 * i + 1];
    const float c = cov2d[4 * i + 3];

    // radius chain with _rn intrinsics: forbids fma contraction (selection-
    // critical, feeds exact bbox-overlap compares)
    const float trace = __fadd_rn(a, c);
    const float det   = __fsub_rn(__fmul_rn(a, c), __fmul_rn(b, b));
    const float tt    = __fmul_rn(trace, trace);
    float arg         = __fsub_rn(tt, __fmul_rn(4.0f, det));
    arg = fmaxf(arg, 0.0f);
    const float t1 = __fmul_rn(0.5f, trace);
    const float t2 = __fmul_rn(0.5f, sqrtf(arg));
    const float lam = fmaxf(__fsub_rn(t1, t2), __fadd_rn(t1, t2));
    const float radius = __fmul_rn(3.0f, sqrtf(lam));

    const float px = pos2d[2 * i];
    const float py = pos2d[2 * i + 1];

    pA[i] = make_float4(px, py, radius, opac[i]);
    pB[i] = make_float4(a, b, c, det);
    pC[i] = make_float4(color[3 * i], color[3 * i + 1], color[3 * i + 2], 0.0f);

    // conservative row range (+/-1 tile margin), then exact test per row
    int ty0 = (int)floorf((py - radius) * 0.0625f) - 1;
    int ty1 = (int)floorf((py + radius) * 0.0625f) + 1;
    ty0 = max(ty0, 0);
    ty1 = min(ty1, TYN - 1);
    const float yp = __fadd_rn(py, radius);
    const float ym = __fsub_rn(py, radius);
    for (int ty = ty0; ty <= ty1; ++ty) {
        const float Tf = (float)(ty * TILE_LEN);
        if ((yp > Tf) && (ym < Tf + (float)TILE_LEN)) {
            const int p = atomicAdd(&counts[ty], 1);
            if (p < ROWCAP) bins[ty * ROWCAP + p] = i;
        }
    }
}

// ---------------------------------------------------------------------------
// Kernel 2: per-row stable depth sort (rank sort over unique 64-bit keys
// (depth_bits << 32) | idx; depth >= 0 so float bits are order-isomorphic).
// One block per tile-row; list (~900 entries) lives in LDS.
// ---------------------------------------------------------------------------
__global__ __launch_bounds__(256) void sort_rows(
    const float* __restrict__ depth, int* __restrict__ counts,
    int* __restrict__ bins)
{
    __shared__ uint64_t keys[ROWCAP];   // 32 KiB
    const int row = blockIdx.x;
    int C = counts[row];
    if (C > ROWCAP) C = ROWCAP;
    int* bl = bins + row * ROWCAP;

    for (int k = threadIdx.x; k < C; k += 256) {
        const int idx = bl[k];
        keys[k] = ((uint64_t)__float_as_uint(depth[idx]) << 32) | (uint32_t)idx;
    }
    __syncthreads();

    for (int k = threadIdx.x; k < C; k += 256) {
        const uint64_t mykey = keys[k];
        int rank = 0;
#pragma unroll 8
        for (int j = 0; j < C; ++j)
            rank += (keys[j] < mykey) ? 1 : 0;
        bl[rank] = (int)(uint32_t)mykey;   // unique ranks -> in-place scatter ok
    }
    if (threadIdx.x == 0 && counts[row] > ROWCAP) counts[row] = ROWCAP;
}

// ---------------------------------------------------------------------------
// Kernel 3: per-tile render. One block per tile, 256 threads = 256 pixels.
// Phase 1: scan this tile-row's depth-sorted bin in chunks of 256,
//          ballot-compact first KMAX x-overlapping gaussians.
// Phase 2: fetch their params to LDS, per-pixel front-to-back blend.
// ---------------------------------------------------------------------------
__global__ __launch_bounds__(256) void render_tiles(
    const float4* __restrict__ pA0, const float4* __restrict__ pB0,
    const float4* __restrict__ pC0, const int* __restrict__ counts,
    const int* __restrict__ bins, float* __restrict__ out)
{
    __shared__ int    s_list[KMAX];
    __shared__ int    s_wcnt[4];
    __shared__ float4 pA[KMAX], pB[KMAX], pC[KMAX];

    const int tile = blockIdx.x;
    const int tx = tile / TYN;
    const int ty = tile % TYN;
    const float Lf = (float)(tx * TILE_LEN);
    const float Tf = (float)(ty * TILE_LEN);
    const int t = threadIdx.x;
    const int lane = t & 63;
    const int w = t >> 6;

    int C = counts[ty];
    if (C > ROWCAP) C = ROWCAP;
    const int* bl = bins + ty * ROWCAP;

    // ---- Phase 1: ordered compaction of first KMAX x-overlapping gaussians
    int count = 0;  // block-uniform
    for (int base = 0; base < C; base += 256) {
        int g = -1;
        bool ov = false;
        if (base + t < C) {
            g = bl[base + t];
            const float4 A = pA0[g];
            ov = (__fadd_rn(A.x, A.z) > Lf) &&
                 (__fsub_rn(A.x, A.z) < Lf + (float)TILE_LEN);
        }
        const unsigned long long m = __ballot(ov);
        if (lane == 0) s_wcnt[w] = __popcll(m);
        __syncthreads();
        const int c0 = s_wcnt[0], c1 = s_wcnt[1], c2 = s_wcnt[2], c3 = s_wcnt[3];
        int off = count;
        if (w > 0) off += c0;
        if (w > 1) off += c1;
        if (w > 2) off += c2;
        const int pos = off + __popcll(m & ((1ull << lane) - 1ull));
        if (ov && pos < KMAX) s_list[pos] = g;
        count = min(KMAX, count + c0 + c1 + c2 + c3);
        __syncthreads();
        if (count >= KMAX) break;
    }

    // ---- fetch selected gaussian params into LDS
    if (t < count) {
        const int g = s_list[t];
        pA[t] = pA0[g];
        pB[t] = pB0[g];
        pC[t] = pC0[g];
    }
    __syncthreads();

    // ---- Phase 2: per-pixel blend (pixel (i,j): x = left+i, y = top+j)
    const int j = t & 15;
    const int i = t >> 4;
    const float x = Lf + (float)i;
    const float y = Tf + (float)j;

    float Tacc = 1.0f, cr = 0.0f, cg = 0.0f, cb = 0.0f;
    for (int k = 0; k < count; ++k) {
        const float4 A = pA[k];
        const float4 B = pB[k];
        const float4 Cc = pC[k];
        const float dx = x - A.x;
        const float dy = y - A.y;
        const float quad = (B.z * dx * dx - 2.0f * B.y * dx * dy + B.x * dy * dy) / B.w;
        const float prob = expf(-0.5f * quad);
        const float alpha = fminf(fmaxf(A.w * prob, 0.01f), 0.99f);
        const float wgt = alpha * Tacc;
        cr = fmaf(wgt, Cc.x, cr);
        cg = fmaf(wgt, Cc.y, cg);
        cb = fmaf(wgt, Cc.z, cb);
        Tacc *= (1.0f - alpha);
    }

    const int X = tx * TILE_LEN + i;
    const int Y = ty * TILE_LEN + j;
    float* o = out + ((size_t)X * IMGW + (size_t)Y) * 3;
    o[0] = cr;
    o[1] = cg;
    o[2] = cb;
}

// ---------------------------------------------------------------------------
extern "C" void kernel_launch(void* const* d_in, const int* in_sizes, int n_in,
                              void* d_out, int out_size, void* d_ws, size_t ws_size,
                              hipStream_t stream)
{
    const float* pos2d = (const float*)d_in[0];
    const float* cov2d = (const float*)d_in[1];
    const float* opac  = (const float*)d_in[2];
    const float* color = (const float*)d_in[3];
    const float* depth = (const float*)d_in[4];
    float* out = (float*)d_out;

    const int N = in_sizes[2];  // opacity count == N_GAUSS

    // workspace layout: pA/pB/pC float4[N] each, counts[32], bins[32*ROWCAP]
    float4* pA = (float4*)d_ws;
    float4* pB = pA + N;
    float4* pC = pB + N;
    int* counts = (int*)(pC + N);
    int* bins = counts + 64;  // 64-int pad keeps bins 256B-aligned

    hipMemsetAsync(counts, 0, 64 * sizeof(int), stream);

    prep<<<(N + 255) / 256, 256, 0, stream>>>(
        pos2d, cov2d, opac, color, pA, pB, pC, counts, bins, N);

    sort_rows<<<TYN, 256, 0, stream>>>(depth, counts, bins);

    render_tiles<<<TXN * TYN, 256, 0, stream>>>(pA, pB, pC, counts, bins, out);
}

// Round 3
// 57.001 us; speedup vs baseline: 2.5894x; 2.5894x over previous
//
#include <hip/hip_runtime.h>
#include <stdint.h>

#define TILE_LEN 16
#define KMAX 64
#define IMGW 512
#define IMGH 512
#define TXN (IMGW / TILE_LEN)   // 32
#define TYN (IMGH / TILE_LEN)   // 32
#define ROWCAP 4096             // per-row bin capacity (expected ~1500)
#define PREPB 1024

// ---------------------------------------------------------------------------
// Kernel 1: per-gaussian prep + row binning with hierarchical atomics.
// pA = (px, py, radius, opacity); pB = (a, b, c, det); pC = (r, g, b, 0)
// indexed by ORIGINAL gaussian index.
// Pass 1: per-block LDS row counts. Reservation: ONE global atomicAdd per
// (block,row). Pass 2: LDS position counters -> scatter into reserved range.
// Append order nondeterministic; sort_rows makes final order deterministic.
// ---------------------------------------------------------------------------
__global__ __launch_bounds__(PREPB) void prep(
    const float* __restrict__ pos2d, const float* __restrict__ cov2d,
    const float* __restrict__ opac,  const float* __restrict__ color,
    float4* __restrict__ pA, float4* __restrict__ pB, float4* __restrict__ pC,
    int* __restrict__ counts, int* __restrict__ bins, int N)
{
    __shared__ int lcnt[TYN];
    __shared__ int lpos[TYN];
    __shared__ int lbase[TYN];

    const int t = threadIdx.x;
    if (t < TYN) { lcnt[t] = 0; lpos[t] = 0; }
    __syncthreads();

    const int i = blockIdx.x * PREPB + t;

    float yp = 0.0f, ym = 0.0f;
    int ty0 = 0, ty1 = -1;

    if (i < N) {
        const float a = cov2d[4 * i + 0];
        const float b = cov2d[4 * i + 1];
        const float c = cov2d[4 * i + 3];

        // radius chain with _rn intrinsics: forbids fma contraction
        // (selection-critical, feeds exact bbox-overlap compares)
        const float trace = __fadd_rn(a, c);
        const float det   = __fsub_rn(__fmul_rn(a, c), __fmul_rn(b, b));
        const float tt    = __fmul_rn(trace, trace);
        float arg         = __fsub_rn(tt, __fmul_rn(4.0f, det));
        arg = fmaxf(arg, 0.0f);
        const float t1 = __fmul_rn(0.5f, trace);
        const float t2 = __fmul_rn(0.5f, sqrtf(arg));
        const float lam = fmaxf(__fsub_rn(t1, t2), __fadd_rn(t1, t2));
        const float radius = __fmul_rn(3.0f, sqrtf(lam));

        const float px = pos2d[2 * i];
        const float py = pos2d[2 * i + 1];

        pA[i] = make_float4(px, py, radius, opac[i]);
        pB[i] = make_float4(a, b, c, det);
        pC[i] = make_float4(color[3 * i], color[3 * i + 1], color[3 * i + 2], 0.0f);

        // conservative row range (+/-1 tile margin), exact test per row below
        ty0 = max((int)floorf((py - radius) * 0.0625f) - 1, 0);
        ty1 = min((int)floorf((py + radius) * 0.0625f) + 1, TYN - 1);
        yp = __fadd_rn(py, radius);
        ym = __fsub_rn(py, radius);

        // pass 1: count row hits in LDS
        for (int ty = ty0; ty <= ty1; ++ty) {
            const float Tf = (float)(ty * TILE_LEN);
            if ((yp > Tf) && (ym < Tf + (float)TILE_LEN))
                atomicAdd(&lcnt[ty], 1);
        }
    }
    __syncthreads();

    // reservation: one global atomic per (block,row)
    if (t < TYN) {
        const int v = lcnt[t];
        lbase[t] = (v > 0) ? atomicAdd(&counts[t], v) : 0;
    }
    __syncthreads();

    // pass 2: scatter into reserved ranges
    if (i < N) {
        for (int ty = ty0; ty <= ty1; ++ty) {
            const float Tf = (float)(ty * TILE_LEN);
            if ((yp > Tf) && (ym < Tf + (float)TILE_LEN)) {
                const int p = atomicAdd(&lpos[ty], 1);
                const int dst = lbase[ty] + p;
                if (dst < ROWCAP) bins[ty * ROWCAP + dst] = i;
            }
        }
    }
}

// ---------------------------------------------------------------------------
// Kernel 2: per-row stable depth sort (rank sort over unique 64-bit keys
// (depth_bits << 32) | idx; depth >= 0 so float bits are order-isomorphic).
// One 1024-thread block per tile-row; list (~1500 entries) lives in LDS.
// ---------------------------------------------------------------------------
__global__ __launch_bounds__(1024) void sort_rows(
    const float* __restrict__ depth, int* __restrict__ counts,
    int* __restrict__ bins)
{
    __shared__ uint64_t keys[ROWCAP];   // 32 KiB
    const int row = blockIdx.x;
    int C = counts[row];
    if (C > ROWCAP) C = ROWCAP;
    int* bl = bins + row * ROWCAP;

    for (int k = threadIdx.x; k < C; k += 1024) {
        const int idx = bl[k];
        keys[k] = ((uint64_t)__float_as_uint(depth[idx]) << 32) | (uint32_t)idx;
    }
    __syncthreads();

    for (int k = threadIdx.x; k < C; k += 1024) {
        const uint64_t mykey = keys[k];
        int rank = 0;
#pragma unroll 8
        for (int j = 0; j < C; ++j)
            rank += (keys[j] < mykey) ? 1 : 0;
        bl[rank] = (int)(uint32_t)mykey;   // unique ranks -> in-place scatter ok
    }
    if (threadIdx.x == 0 && counts[row] > ROWCAP) counts[row] = ROWCAP;
}

// ---------------------------------------------------------------------------
// Kernel 3: per-tile render. One block per tile, 256 threads = 256 pixels.
// Phase 1: scan this tile-row's depth-sorted bin in chunks of 256,
//          ballot-compact first KMAX x-overlapping gaussians.
// Phase 2: fetch their params to LDS, per-pixel front-to-back blend.
// ---------------------------------------------------------------------------
__global__ __launch_bounds__(256) void render_tiles(
    const float4* __restrict__ pA0, const float4* __restrict__ pB0,
    const float4* __restrict__ pC0, const int* __restrict__ counts,
    const int* __restrict__ bins, float* __restrict__ out)
{
    __shared__ int    s_list[KMAX];
    __shared__ int    s_wcnt[4];
    __shared__ float4 pA[KMAX], pB[KMAX], pC[KMAX];

    const int tile = blockIdx.x;
    const int tx = tile / TYN;
    const int ty = tile % TYN;
    const float Lf = (float)(tx * TILE_LEN);
    const float Tf = (float)(ty * TILE_LEN);
    const int t = threadIdx.x;
    const int lane = t & 63;
    const int w = t >> 6;

    int C = counts[ty];
    if (C > ROWCAP) C = ROWCAP;
    const int* bl = bins + ty * ROWCAP;

    // ---- Phase 1: ordered compaction of first KMAX x-overlapping gaussians
    int count = 0;  // block-uniform
    for (int base = 0; base < C; base += 256) {
        int g = -1;
        bool ov = false;
        if (base + t < C) {
            g = bl[base + t];
            const float4 A = pA0[g];
            ov = (__fadd_rn(A.x, A.z) > Lf) &&
                 (__fsub_rn(A.x, A.z) < Lf + (float)TILE_LEN);
        }
        const unsigned long long m = __ballot(ov);
        if (lane == 0) s_wcnt[w] = __popcll(m);
        __syncthreads();
        const int c0 = s_wcnt[0], c1 = s_wcnt[1], c2 = s_wcnt[2], c3 = s_wcnt[3];
        int off = count;
        if (w > 0) off += c0;
        if (w > 1) off += c1;
        if (w > 2) off += c2;
        const int pos = off + __popcll(m & ((1ull << lane) - 1ull));
        if (ov && pos < KMAX) s_list[pos] = g;
        count = min(KMAX, count + c0 + c1 + c2 + c3);
        __syncthreads();
        if (count >= KMAX) break;
    }

    // ---- fetch selected gaussian params into LDS
    if (t < count) {
        const int g = s_list[t];
        pA[t] = pA0[g];
        pB[t] = pB0[g];
        pC[t] = pC0[g];
    }
    __syncthreads();

    // ---- Phase 2: per-pixel blend (pixel (i,j): x = left+i, y = top+j)
    const int j = t & 15;
    const int i = t >> 4;
    const float x = Lf + (float)i;
    const float y = Tf + (float)j;

    float Tacc = 1.0f, cr = 0.0f, cg = 0.0f, cb = 0.0f;
    for (int k = 0; k < count; ++k) {
        const float4 A = pA[k];
        const float4 B = pB[k];
        const float4 Cc = pC[k];
        const float dx = x - A.x;
        const float dy = y - A.y;
        const float quad = (B.z * dx * dx - 2.0f * B.y * dx * dy + B.x * dy * dy) / B.w;
        const float prob = expf(-0.5f * quad);
        const float alpha = fminf(fmaxf(A.w * prob, 0.01f), 0.99f);
        const float wgt = alpha * Tacc;
        cr = fmaf(wgt, Cc.x, cr);
        cg = fmaf(wgt, Cc.y, cg);
        cb = fmaf(wgt, Cc.z, cb);
        Tacc *= (1.0f - alpha);
    }

    const int X = tx * TILE_LEN + i;
    const int Y = ty * TILE_LEN + j;
    float* o = out + ((size_t)X * IMGW + (size_t)Y) * 3;
    o[0] = cr;
    o[1] = cg;
    o[2] = cb;
}

// ---------------------------------------------------------------------------
extern "C" void kernel_launch(void* const* d_in, const int* in_sizes, int n_in,
                              void* d_out, int out_size, void* d_ws, size_t ws_size,
                              hipStream_t stream)
{
    const float* pos2d = (const float*)d_in[0];
    const float* cov2d = (const float*)d_in[1];
    const float* opac  = (const float*)d_in[2];
    const float* color = (const float*)d_in[3];
    const float* depth = (const float*)d_in[4];
    float* out = (float*)d_out;

    const int N = in_sizes[2];  // opacity count == N_GAUSS

    // workspace layout: pA/pB/pC float4[N] each, counts[32], bins[32*ROWCAP]
    float4* pA = (float4*)d_ws;
    float4* pB = pA + N;
    float4* pC = pB + N;
    int* counts = (int*)(pC + N);
    int* bins = counts + 64;  // 64-int pad keeps bins 256B-aligned

    hipMemsetAsync(counts, 0, 64 * sizeof(int), stream);

    prep<<<(N + PREPB - 1) / PREPB, PREPB, 0, stream>>>(
        pos2d, cov2d, opac, color, pA, pB, pC, counts, bins, N);

    sort_rows<<<TYN, 1024, 0, stream>>>(depth, counts, bins);

    render_tiles<<<TXN * TYN, 256, 0, stream>>>(pA, pB, pC, counts, bins, out);
}